// Round 2
// baseline (261.427 us; speedup 1.0000x reference)
//
#include <hip/hip_runtime.h>
#include <hip/hip_bf16.h>

// Problem constants
#define SZ    2048
#define SLEN  128
#define DWE   100
#define DPE   5
#define DEE   100
#define DC    300
#define CIN   210
#define KLOC  10
#define OUTW  1500
#define DR    34

// GEMM layout: only word(100)+pos1(5)+pos2(5)=110 channels go through MFMA.
#define KP    128    // padded K
#define LCOLS 136    // XT row stride in bf16 elems (272 B -> 2-way bank spread, free)
#define LROWS 130    // 128 tokens + 2 zero pad rows
#define CPAD  320    // padded out-channels

typedef short short8 __attribute__((ext_vector_type(8)));
typedef float f32x4 __attribute__((ext_vector_type(4)));

static __device__ __forceinline__ unsigned short f2b(float f) {
  return __builtin_bit_cast(unsigned short, __float2bfloat16(f));
}

// wk[kk][c][i] bf16 [3][320][128]; real for c<300, i<110, else 0
__global__ void prep_wk(const float* __restrict__ conv_w, unsigned short* __restrict__ wk) {
  int idx = blockIdx.x * 256 + threadIdx.x;
  if (idx >= 3 * CPAD * KP) return;
  int i  = idx & (KP - 1);
  int c  = (idx / KP) % CPAD;
  int kk = idx / (KP * CPAD);
  float v = 0.f;
  if (c < DC && i < 110) v = conv_w[(c * CIN + i) * 3 + kk];
  wk[idx] = f2b(v);
}

// evconv[st][kk][c] fp32: event-channel conv contribution per tap (+bias folded into kk==1)
__global__ void prep_ev(const float* __restrict__ conv_w, const float* __restrict__ event_emb,
                        const float* __restrict__ conv_b, float* __restrict__ evconv) {
  int idx = blockIdx.x * 256 + threadIdx.x;
  if (idx >= DR * 3 * DC) return;
  int c  = idx % DC;
  int kk = (idx / DC) % 3;
  int st = idx / (3 * DC);
  float v = 0.f;
  if (st != 0) {  // padding_idx=0 on event_emb
    const float* wrow = conv_w + (c * CIN + 110) * 3 + kk;  // stride 3 over i
    const float* e = event_emb + st * DEE;
    for (int i = 0; i < DEE; ++i) v += wrow[3 * i] * e[i];
  }
  if (kk == 1) v += conv_b[c];
  evconv[idx] = v;
}

__global__ __launch_bounds__(256, 2) void dmcnn_main(
    const int* __restrict__ inp, const int* __restrict__ pos1, const int* __restrict__ pos2,
    const int* __restrict__ loc, const int* __restrict__ loc_mark, const int* __restrict__ subtype,
    const float* __restrict__ maskL, const float* __restrict__ maskM, const float* __restrict__ maskR,
    const float* __restrict__ word_emb, const float* __restrict__ pos_emb,
    const unsigned short* __restrict__ wk, const float* __restrict__ evconv,
    float* __restrict__ out)
{
  __shared__ unsigned short XT[LROWS * LCOLS];  // 35360 B; XT[t+1][i]
  __shared__ int cw[4];                         // per-wave popcounts of maskL/maskM

  const int s   = blockIdx.x;
  const int tid = threadIdx.x;

  // ---- phase 0 (disjoint writes, single barrier after) ----
  // zero pad rows 0 and 129 (cols 0..127; cols 128..135 never read)
  if (tid < 64)        ((unsigned*)XT)[tid] = 0u;
  else if (tid < 128)  ((unsigned*)(XT + 129 * LCOLS))[tid - 64] = 0u;

  // recover cut points a,b from the masks via ballot (t = tid for waves 0,1)
  if (tid < 128) {
    const int inL = maskL[s * SLEN + tid] > 0.5f;
    const int inM = maskM[s * SLEN + tid] > 0.5f;
    unsigned long long bL = __ballot(inL);
    unsigned long long bM = __ballot(inM);
    if ((tid & 63) == 0) {
      cw[tid >> 6]     = __popcll(bL);
      cw[2 + (tid >> 6)] = __popcll(bM);
    }
  }

  // stage XT: 2 threads per token
  {
    const int t = tid >> 1, half = tid & 1;
    unsigned short* row = &XT[(t + 1) * LCOLS];
    const int w = inp[s * SLEN + t];
    const float* wp = word_emb + (size_t)w * DWE + half * 50;
    #pragma unroll
    for (int j = 0; j < 25; ++j) {
      unsigned u = 0u;
      if (w != 0) {  // padding_idx=0
        float2 v = ((const float2*)wp)[j];
        u = (unsigned)f2b(v.x) | ((unsigned)f2b(v.y) << 16);
      }
      *(unsigned*)&row[half * 50 + j * 2] = u;
    }
    const int p = (half == 0 ? pos1 : pos2)[s * SLEN + t];
    const float* pp = pos_emb + p * DPE;
    #pragma unroll
    for (int d = 0; d < DPE; ++d) row[DWE + half * DPE + d] = f2b(pp[d]);
    #pragma unroll
    for (int d = 0; d < 9; ++d) row[110 + 9 * half + d] = 0;  // K-pad cols 110..127
  }
  __syncthreads();

  // ---- GEMM: wave wv owns channels [80wv, 80wv+80), all 128 t ----
  const int wv   = tid >> 6;
  const int lane = tid & 63;
  const int r16  = lane & 15, q16 = lane >> 4;

  f32x4 acc[8][5];
  #pragma unroll
  for (int tt = 0; tt < 8; ++tt)
    #pragma unroll
    for (int ci = 0; ci < 5; ++ci) acc[tt][ci] = (f32x4){0.f, 0.f, 0.f, 0.f};

  const unsigned short* wbase = wk + (size_t)(80 * wv + r16) * KP + q16 * 8;
  #pragma unroll
  for (int ks = 0; ks < 12; ++ks) {
    const int kk = ks >> 2, kt = ks & 3;
    short8 wf[5];
    #pragma unroll
    for (int ci = 0; ci < 5; ++ci)
      wf[ci] = *(const short8*)(wbase + (size_t)(kk * CPAD + 16 * ci) * KP + kt * 32);
    #pragma unroll
    for (int tt = 0; tt < 8; ++tt) {
      short8 xf = *(const short8*)&XT[(16 * tt + r16 + kk) * LCOLS + kt * 32 + q16 * 8];
      #pragma unroll
      for (int ci = 0; ci < 5; ++ci)
        acc[tt][ci] = __builtin_amdgcn_mfma_f32_16x16x32_bf16(xf, wf[ci], acc[tt][ci], 0, 0, 0);
    }
  }

  // ---- epilogue: D[row=t][col=c]; t = 16tt+4q16+j, c = 80wv+16ci+r16 ----
  const int acut = cw[0] + cw[1];
  const int bcut = acut + cw[2] + cw[3];
  const int st   = subtype[s];
  const float* evc = evconv + (size_t)st * 3 * DC;
  float* orow = out + (size_t)s * OUTW;

  #pragma unroll
  for (int ci = 0; ci < 5; ++ci) {
    const int c = 80 * wv + 16 * ci + r16;
    if (c < DC) {
      const float s0 = evc[c], s1 = evc[DC + c], s2 = evc[2 * DC + c];
      const float base = s0 + s1 + s2;   // bias already folded into s1
      float rL = 0.f, rM = 0.f, rR = 0.f;  // masked-out positions contribute 0
      #pragma unroll
      for (int tt = 0; tt < 8; ++tt) {
        #pragma unroll
        for (int j = 0; j < 4; ++j) {
          const int t = 16 * tt + 4 * q16 + j;
          float v = acc[tt][ci][j] + base;
          if (t == 0)   v -= s0;   // top boundary: no tap kk=0
          if (t == 127) v -= s2;   // bottom boundary: no tap kk=2
          if (t < acut)      rL = fmaxf(rL, v);
          else if (t < bcut) rM = fmaxf(rM, v);
          else               rR = fmaxf(rR, v);
        }
      }
      #pragma unroll
      for (int off = 16; off < 64; off <<= 1) {
        rL = fmaxf(rL, __shfl_xor(rL, off));
        rM = fmaxf(rM, __shfl_xor(rM, off));
        rR = fmaxf(rR, __shfl_xor(rR, off));
      }
      if (q16 == 0) {
        orow[c]          = tanhf(rL);
        orow[DC + c]     = tanhf(rM);
        orow[2 * DC + c] = tanhf(rR);
      }
    }
  }

  // ---- loc_embeds: out[s][900..1499], exact fp32 ----
  const int mark = loc_mark[s];
  for (int j = tid; j < 600; j += 256) {
    float v;
    if (j < 400) {
      const int k = j / 100, d = j % 100;
      const int idx = loc[s * KLOC + k];
      v = (idx == 0) ? 0.f : word_emb[(size_t)idx * DWE + d];
    } else if (j < 500) {
      const int d = j - 400;
      float sum = 0.f;
      for (int k = 4; k < 4 + mark; ++k) {
        const int idx = loc[s * KLOC + k];
        sum += (idx == 0) ? 0.f : word_emb[(size_t)idx * DWE + d];
      }
      v = sum / (float)mark;
    } else {
      const int d = j - 500;
      const int idx = loc[s * KLOC + 4 + mark];
      v = (idx == 0) ? 0.f : word_emb[(size_t)idx * DWE + d];
    }
    orow[900 + j] = tanhf(v);
  }
}

extern "C" void kernel_launch(void* const* d_in, const int* in_sizes, int n_in,
                              void* d_out, int out_size, void* d_ws, size_t ws_size,
                              hipStream_t stream) {
  const int*   inp       = (const int*)d_in[0];
  const int*   pos1      = (const int*)d_in[1];
  const int*   pos2      = (const int*)d_in[2];
  const int*   loc       = (const int*)d_in[3];
  const int*   loc_mark  = (const int*)d_in[4];
  const int*   subtype   = (const int*)d_in[5];
  const float* maskL     = (const float*)d_in[6];
  const float* maskM     = (const float*)d_in[7];
  const float* maskR     = (const float*)d_in[8];
  const float* word_emb  = (const float*)d_in[9];
  const float* pos_emb   = (const float*)d_in[10];
  const float* event_emb = (const float*)d_in[11];
  const float* conv_w    = (const float*)d_in[12];
  const float* conv_b    = (const float*)d_in[13];

  unsigned short* wk = (unsigned short*)d_ws;                    // 3*320*128*2 = 245760 B
  float* evconv = (float*)((char*)d_ws + 3 * CPAD * KP * 2);     // 34*3*300*4 = 122400 B
  float* out = (float*)d_out;

  prep_wk<<<(3 * CPAD * KP + 255) / 256, 256, 0, stream>>>(conv_w, wk);
  prep_ev<<<(DR * 3 * DC + 255) / 256, 256, 0, stream>>>(conv_w, event_emb, conv_b, evconv);
  dmcnn_main<<<SZ, 256, 0, stream>>>(inp, pos1, pos2, loc, loc_mark, subtype,
      maskL, maskM, maskR, word_emb, pos_emb, wk, evconv, out);
}